// Round 2
// baseline (173.317 us; speedup 1.0000x reference)
//
#include <hip/hip_runtime.h>
#include <cstddef>

#define EPS 1e-6f
constexpr float INV_SQRT_E = 0.6065306597126334f;  // exp(-0.5*THETA^2), THETA=1

// One kernel instantiation per dilation D.
// Tile 64 wide x 16 tall; block (64,16) = 16 waves, ONE output row per thread.
// Grid 512 blocks -> 2 blocks/CU -> 32 waves/CU if VGPR<=64 (launch_bounds 8/EU).
// LDS holds float2 {v, v*log(v+eps)} so pass-1 gets both with one ds_read_b64.
template <int D>
__global__ __launch_bounds__(1024, 8) void tex_kernel(
    const float* __restrict__ x, float* __restrict__ out, int H, int W)
{
    constexpr int PAD = D * D;          // halo per side
    constexpr int KS  = 2 * D + 1;      // taps per axis
    constexpr int K   = KS * KS;        // patch size
    constexpr int TW  = 64, TH = 16;
    constexpr int LW  = TW + 2 * PAD;
    constexpr int LH  = TH + 2 * PAD;
    constexpr float INVK = 1.0f / (float)K;
    constexpr float UNB  = (float)K / (float)(K - 1);

    __shared__ float2 sv[LH * LW];      // {v, v*log(v+eps)}, zero-padded halo

    const int bc = blockIdx.z;
    const int w0 = blockIdx.x * TW;
    const int h0 = blockIdx.y * TH;
    const float* xp = x + (size_t)bc * H * W;

    // Cooperative staging of tile + halo (zeros outside the image).
    const int tid = threadIdx.y * 64 + threadIdx.x;
    for (int idx = tid; idx < LH * LW; idx += 1024) {
        const int r  = idx / LW;
        const int cc = idx - r * LW;
        const int gh = h0 - PAD + r;
        const int gw = w0 - PAD + cc;
        float v = 0.0f;
        if (gh >= 0 && gh < H && gw >= 0 && gw < W) v = xp[gh * W + gw];
        sv[idx] = make_float2(v, v * __logf(v + EPS));  // v=0 -> exactly 0
    }
    __syncthreads();

    const int tx = threadIdx.x;
    const int ty = threadIdx.y;                    // output row in tile
    const float2* base = &sv[ty * LW + tx];        // taps at const offsets

    float s = 0.0f, s2 = 0.0f, sl = 0.0f;
    float sad;

    if constexpr (K <= 9) {
        // Single pass: cache taps in registers, SAD from regs.
        float ta[K];
        #pragma unroll
        for (int mi = 0; mi < KS; ++mi)
            #pragma unroll
            for (int mj = 0; mj < KS; ++mj) {
                const float2 p = base[(mi * D) * LW + mj * D];
                ta[mi * KS + mj] = p.x;
                s  += p.x;
                s2  = fmaf(p.x, p.x, s2);
                sl += p.y;
            }
        const float mu = s * INVK;
        sad = 0.0f;
        #pragma unroll
        for (int i = 0; i < K; ++i) sad += fabsf(ta[i] - mu);
    } else {
        // Pass 1: linear stats (one b64 read per tap).
        #pragma unroll
        for (int mi = 0; mi < KS; ++mi)
            #pragma unroll
            for (int mj = 0; mj < KS; ++mj) {
                const float2 p = base[(mi * D) * LW + mj * D];
                s  += p.x;
                s2  = fmaf(p.x, p.x, s2);
                sl += p.y;
            }
        const float mu = s * INVK;
        // Pass 2: SAD (mu is per-pixel; not separable).
        sad = 0.0f;
        #pragma unroll
        for (int mi = 0; mi < KS; ++mi)
            #pragma unroll
            for (int mj = 0; mj < KS; ++mj)
                sad += fabsf(base[(mi * D) * LW + mj * D].x - mu);
    }

    const float mu       = s * INVK;
    const float energy   = s2 * INVK;
    const float var      = fmaxf(energy - mu * mu, 0.0f);
    const float sd       = sqrtf(var * UNB) + EPS;
    const float contrast = var / (sd * sd);
    const float entropy  = -sl * INVK;
    const float homog    = 1.0f / (1.0f + sad * INVK);

    const size_t fstride = (size_t)H * W;
    const size_t rowoff  = (size_t)(h0 + ty) * W;
    float* op = out + (size_t)bc * 4 * fstride + w0 + tx;
    op[0 * fstride + rowoff] = (contrast + EPS) * INV_SQRT_E;
    op[1 * fstride + rowoff] = (energy   + EPS) * INV_SQRT_E;
    op[2 * fstride + rowoff] = (entropy  + EPS) * INV_SQRT_E;
    op[3 * fstride + rowoff] = (homog    + EPS) * INV_SQRT_E;
}

extern "C" void kernel_launch(void* const* d_in, const int* in_sizes, int n_in,
                              void* d_out, int out_size, void* d_ws, size_t ws_size,
                              hipStream_t stream) {
    const float* x = (const float*)d_in[0];
    float* out = (float*)d_out;

    const int B = 2, C = 4, H = 256, W = 256;
    const size_t per = (size_t)B * C * 4 * H * W;

    dim3 blk(64, 16, 1);
    dim3 grd(W / 64, H / 16, B * C);
    tex_kernel<1><<<grd, blk, 0, stream>>>(x, out + 0 * per, H, W);
    tex_kernel<2><<<grd, blk, 0, stream>>>(x, out + 1 * per, H, W);
    tex_kernel<3><<<grd, blk, 0, stream>>>(x, out + 2 * per, H, W);
    tex_kernel<4><<<grd, blk, 0, stream>>>(x, out + 3 * per, H, W);
}

// Round 3
// 114.368 us; speedup vs baseline: 1.5154x; 1.5154x over previous
//
#include <hip/hip_runtime.h>
#include <cstddef>

#define EPS 1e-6f
constexpr float INV_SQRT_E = 0.6065306597126334f;  // exp(-0.5*THETA^2), THETA=1

// Fused: all 4 dilations in one launch. blockIdx.z = dilation*8 + (b*C+c).
// Tile 64x16, block (64,16) = 16 waves, one output row per thread.
// launch_bounds(1024,4) -> 64-VGPR budget: no spills (R2's 32-VGPR cap caused
// 300+ MB of scratch traffic per dispatch).
template <int D>
__device__ __forceinline__ void body(const float* __restrict__ x,
                                     float* __restrict__ out,
                                     char* smem, int bc, int H, int W)
{
    constexpr int PAD = D * D;          // halo per side
    constexpr int KS  = 2 * D + 1;      // taps per axis
    constexpr int K   = KS * KS;        // patch size
    constexpr int TW  = 64, TH = 16;
    constexpr int LW  = TW + 2 * PAD;
    constexpr int LH  = TH + 2 * PAD;
    constexpr float INVK = 1.0f / (float)K;
    constexpr float UNB  = (float)K / (float)(K - 1);

    float2* sv = (float2*)smem;         // {v, v*log(v+eps)}, zero-padded halo

    const int w0 = blockIdx.x * TW;
    const int h0 = blockIdx.y * TH;
    const float* xp = x + (size_t)bc * H * W;

    const int tid = threadIdx.y * 64 + threadIdx.x;
    for (int idx = tid; idx < LH * LW; idx += 1024) {
        const int r  = idx / LW;
        const int cc = idx - r * LW;
        const int gh = h0 - PAD + r;
        const int gw = w0 - PAD + cc;
        float v = 0.0f;
        if (gh >= 0 && gh < H && gw >= 0 && gw < W) v = xp[gh * W + gw];
        sv[idx] = make_float2(v, v * __logf(v + EPS));  // v=0 -> exactly 0
    }
    __syncthreads();

    const int tx = threadIdx.x;
    const int ty = threadIdx.y;
    const float2* base = &sv[ty * LW + tx];

    float s = 0.0f, s2 = 0.0f, sl = 0.0f;
    float sad;

    if constexpr (K <= 25) {
        // Single pass: cache taps in registers (fits 64-VGPR budget for K<=25).
        float ta[K];
        #pragma unroll
        for (int mi = 0; mi < KS; ++mi)
            #pragma unroll
            for (int mj = 0; mj < KS; ++mj) {
                const float2 p = base[(mi * D) * LW + mj * D];
                ta[mi * KS + mj] = p.x;
                s  += p.x;
                s2  = fmaf(p.x, p.x, s2);
                sl += p.y;
            }
        const float mu = s * INVK;
        sad = 0.0f;
        #pragma unroll
        for (int i = 0; i < K; ++i) sad += fabsf(ta[i] - mu);
    } else {
        // Pass 1: linear stats (one ds_read_b64 per tap).
        #pragma unroll
        for (int mi = 0; mi < KS; ++mi)
            #pragma unroll
            for (int mj = 0; mj < KS; ++mj) {
                const float2 p = base[(mi * D) * LW + mj * D];
                s  += p.x;
                s2  = fmaf(p.x, p.x, s2);
                sl += p.y;
            }
        const float mu = s * INVK;
        // Pass 2: SAD re-read (.x only -> ds_read_b32, 2-way aliasing = free).
        sad = 0.0f;
        #pragma unroll
        for (int mi = 0; mi < KS; ++mi)
            #pragma unroll
            for (int mj = 0; mj < KS; ++mj)
                sad += fabsf(base[(mi * D) * LW + mj * D].x - mu);
    }

    const float mu       = s * INVK;
    const float energy   = s2 * INVK;
    const float var      = fmaxf(energy - mu * mu, 0.0f);
    const float sd       = sqrtf(var * UNB) + EPS;
    const float contrast = var / (sd * sd);
    const float entropy  = -sl * INVK;
    const float homog    = 1.0f / (1.0f + sad * INVK);

    const size_t fstride = (size_t)H * W;
    const size_t rowoff  = (size_t)(h0 + ty) * W;
    float* op = out + (size_t)bc * 4 * fstride + w0 + tx;
    op[0 * fstride + rowoff] = (contrast + EPS) * INV_SQRT_E;
    op[1 * fstride + rowoff] = (energy   + EPS) * INV_SQRT_E;
    op[2 * fstride + rowoff] = (entropy  + EPS) * INV_SQRT_E;
    op[3 * fstride + rowoff] = (homog    + EPS) * INV_SQRT_E;
}

__global__ __launch_bounds__(1024, 4) void tex_fused(
    const float* __restrict__ x, float* __restrict__ out, int H, int W)
{
    extern __shared__ char smem[];
    const int bc = blockIdx.z & 7;       // b*C + c
    const int dz = blockIdx.z >> 3;      // dilation index 0..3
    const size_t per = (size_t)8 * 4 * H * W;  // elems per dilation output
    switch (dz) {
        case 0: body<1>(x, out + 0 * per, smem, bc, H, W); break;
        case 1: body<2>(x, out + 1 * per, smem, bc, H, W); break;
        case 2: body<3>(x, out + 2 * per, smem, bc, H, W); break;
        default: body<4>(x, out + 3 * per, smem, bc, H, W); break;
    }
}

extern "C" void kernel_launch(void* const* d_in, const int* in_sizes, int n_in,
                              void* d_out, int out_size, void* d_ws, size_t ws_size,
                              hipStream_t stream) {
    const float* x = (const float*)d_in[0];
    float* out = (float*)d_out;

    const int H = 256, W = 256;
    // Max LDS: D=4 -> LH=48, LW=96, float2 -> 48*96*8 = 36864 B
    const size_t smem_bytes = 48 * 96 * sizeof(float2);

    dim3 blk(64, 16, 1);
    dim3 grd(W / 64, H / 16, 4 * 8);     // 4 dilations x (B*C=8)
    tex_fused<<<grd, blk, smem_bytes, stream>>>(x, out, H, W);
}

// Round 4
// 114.180 us; speedup vs baseline: 1.5179x; 1.0016x over previous
//
#include <hip/hip_runtime.h>
#include <cstddef>

#define EPS 1e-6f
constexpr float INV_SQRT_E = 0.6065306597126334f;  // exp(-0.5*THETA^2), THETA=1

// Fused: all 4 dilations in one launch. blockIdx.z = dilation*8 + (b*C+c).
// Tile 64x16, block (64,16) = 16 waves, one output row per thread.
// Register-cache path ONLY for D=1 (K=9): R3 showed K=25 register caching
// spills at the 64-VGPR tier (~120 MB scratch traffic per dispatch).
template <int D>
__device__ __forceinline__ void body(const float* __restrict__ x,
                                     float* __restrict__ out,
                                     char* smem, int bc, int H, int W)
{
    constexpr int PAD = D * D;          // halo per side
    constexpr int KS  = 2 * D + 1;      // taps per axis
    constexpr int K   = KS * KS;        // patch size
    constexpr int TW  = 64, TH = 16;
    constexpr int LW  = TW + 2 * PAD;
    constexpr int LH  = TH + 2 * PAD;
    constexpr float INVK = 1.0f / (float)K;
    constexpr float UNB  = (float)K / (float)(K - 1);

    float2* sv = (float2*)smem;         // {v, v*log(v+eps)}, zero-padded halo

    const int w0 = blockIdx.x * TW;
    const int h0 = blockIdx.y * TH;
    const float* xp = x + (size_t)bc * H * W;

    const int tid = threadIdx.y * 64 + threadIdx.x;
    for (int idx = tid; idx < LH * LW; idx += 1024) {
        const int r  = idx / LW;
        const int cc = idx - r * LW;
        const int gh = h0 - PAD + r;
        const int gw = w0 - PAD + cc;
        float v = 0.0f;
        if (gh >= 0 && gh < H && gw >= 0 && gw < W) v = xp[gh * W + gw];
        sv[idx] = make_float2(v, v * __logf(v + EPS));  // v=0 -> exactly 0
    }
    __syncthreads();

    const int tx = threadIdx.x;
    const int ty = threadIdx.y;
    const float2* base = &sv[ty * LW + tx];

    float s = 0.0f, s2 = 0.0f, sl = 0.0f;
    float sad;

    if constexpr (K <= 9) {
        // Single pass: cache 9 taps in registers (fits 64-VGPR tier).
        float ta[K];
        #pragma unroll
        for (int mi = 0; mi < KS; ++mi)
            #pragma unroll
            for (int mj = 0; mj < KS; ++mj) {
                const float2 p = base[(mi * D) * LW + mj * D];
                ta[mi * KS + mj] = p.x;
                s  += p.x;
                s2  = fmaf(p.x, p.x, s2);
                sl += p.y;
            }
        const float mu = s * INVK;
        sad = 0.0f;
        #pragma unroll
        for (int i = 0; i < K; ++i) sad += fabsf(ta[i] - mu);
    } else {
        // Pass 1: linear stats (one ds_read_b64 per tap).
        #pragma unroll
        for (int mi = 0; mi < KS; ++mi)
            #pragma unroll
            for (int mj = 0; mj < KS; ++mj) {
                const float2 p = base[(mi * D) * LW + mj * D];
                s  += p.x;
                s2  = fmaf(p.x, p.x, s2);
                sl += p.y;
            }
        const float mu = s * INVK;
        // Pass 2: SAD re-read (mu is per-pixel; not separable).
        sad = 0.0f;
        #pragma unroll
        for (int mi = 0; mi < KS; ++mi)
            #pragma unroll
            for (int mj = 0; mj < KS; ++mj)
                sad += fabsf(base[(mi * D) * LW + mj * D].x - mu);
    }

    const float mu       = s * INVK;
    const float energy   = s2 * INVK;
    const float var      = fmaxf(energy - mu * mu, 0.0f);
    const float sd       = sqrtf(var * UNB) + EPS;
    const float contrast = var / (sd * sd);
    const float entropy  = -sl * INVK;
    const float homog    = 1.0f / (1.0f + sad * INVK);

    const size_t fstride = (size_t)H * W;
    const size_t rowoff  = (size_t)(h0 + ty) * W;
    float* op = out + (size_t)bc * 4 * fstride + w0 + tx;
    op[0 * fstride + rowoff] = (contrast + EPS) * INV_SQRT_E;
    op[1 * fstride + rowoff] = (energy   + EPS) * INV_SQRT_E;
    op[2 * fstride + rowoff] = (entropy  + EPS) * INV_SQRT_E;
    op[3 * fstride + rowoff] = (homog    + EPS) * INV_SQRT_E;
}

__global__ __launch_bounds__(1024, 4) void tex_fused(
    const float* __restrict__ x, float* __restrict__ out, int H, int W)
{
    extern __shared__ char smem[];
    const int bc = blockIdx.z & 7;       // b*C + c
    const int dz = blockIdx.z >> 3;      // dilation index 0..3
    const size_t per = (size_t)8 * 4 * H * W;  // elems per dilation output
    switch (dz) {
        case 0: body<1>(x, out + 0 * per, smem, bc, H, W); break;
        case 1: body<2>(x, out + 1 * per, smem, bc, H, W); break;
        case 2: body<3>(x, out + 2 * per, smem, bc, H, W); break;
        default: body<4>(x, out + 3 * per, smem, bc, H, W); break;
    }
}

extern "C" void kernel_launch(void* const* d_in, const int* in_sizes, int n_in,
                              void* d_out, int out_size, void* d_ws, size_t ws_size,
                              hipStream_t stream) {
    const float* x = (const float*)d_in[0];
    float* out = (float*)d_out;

    const int H = 256, W = 256;
    // Max LDS: D=4 -> LH=48, LW=96, float2 -> 48*96*8 = 36864 B
    const size_t smem_bytes = 48 * 96 * sizeof(float2);

    dim3 blk(64, 16, 1);
    dim3 grd(W / 64, H / 16, 4 * 8);     // 4 dilations x (B*C=8)
    tex_fused<<<grd, blk, smem_bytes, stream>>>(x, out, H, W);
}

// Round 5
// 85.670 us; speedup vs baseline: 2.0231x; 1.3328x over previous
//
#include <hip/hip_runtime.h>
#include <cstddef>

#define EPS 1e-6f
constexpr float INV_SQRT_E = 0.6065306597126334f;  // exp(-0.5*THETA^2), THETA=1

// Fused, all 4 dilations in one launch. blockIdx.z = (b*C+c)*4 + dz so
// dilations interleave at 64-block granularity (load balance across CUs).
// Tile 64x16, block (64,16) = 16 waves, one output row per thread.
// Pass-1 (s, s^2, sum p*log p) is SEPARABLE: horizontal row-sums staged in
// LDS, then KS vertical taps. SAD (pass 2) stays K-tap (mu is per-pixel).
// LDS budget 73728 B/block -> 2 blocks/CU (147 KB < 160 KB).
// Output stores are nontemporal: streaming-only, avoids L2 write-allocate
// RMW fetches (~37 MB of R4's FETCH_SIZE was output-sized).
template <int D>
__device__ __forceinline__ void body(const float* __restrict__ x,
                                     float* __restrict__ out,
                                     char* smem, int bc, int H, int W)
{
    constexpr int PAD = D * D;          // halo per side
    constexpr int KS  = 2 * D + 1;      // taps per axis
    constexpr int K   = KS * KS;        // patch size
    constexpr int TW  = 64, TH = 16;
    constexpr int LW  = TW + 2 * PAD;
    constexpr int LH  = TH + 2 * PAD;
    constexpr float INVK = 1.0f / (float)K;
    constexpr float UNB  = (float)K / (float)(K - 1);

    float2* sv = (float2*)smem;                         // {v, v*log(v+eps)}
    float2* rs2 = (float2*)(smem + LH * LW * 8);        // {row_s, row_s2}
    float*  rs1 = (float*) (smem + LH * LW * 8 + LH * 64 * 8);  // row_sl

    const int w0 = blockIdx.x * TW;
    const int h0 = blockIdx.y * TH;
    const float* xp = x + (size_t)bc * H * W;

    const int tid = threadIdx.y * 64 + threadIdx.x;
    for (int idx = tid; idx < LH * LW; idx += 1024) {
        const int r  = idx / LW;
        const int cc = idx - r * LW;
        const int gh = h0 - PAD + r;
        const int gw = w0 - PAD + cc;
        float v = 0.0f;
        if (gh >= 0 && gh < H && gw >= 0 && gw < W) v = xp[gh * W + gw];
        sv[idx] = make_float2(v, v * __logf(v + EPS));  // v=0 -> exactly 0
    }
    __syncthreads();

    const int tx = threadIdx.x;
    const int ty = threadIdx.y;

    float s = 0.0f, s2 = 0.0f, sl = 0.0f;
    float sad;

    if constexpr (K <= 9) {
        // D=1: single pass, taps cached in registers.
        const float2* base = &sv[ty * LW + tx];
        float ta[K];
        #pragma unroll
        for (int mi = 0; mi < KS; ++mi)
            #pragma unroll
            for (int mj = 0; mj < KS; ++mj) {
                const float2 p = base[(mi * D) * LW + mj * D];
                ta[mi * KS + mj] = p.x;
                s  += p.x;
                s2  = fmaf(p.x, p.x, s2);
                sl += p.y;
            }
        const float mu = s * INVK;
        sad = 0.0f;
        #pragma unroll
        for (int i = 0; i < K; ++i) sad += fabsf(ta[i] - mu);
    } else {
        // Horizontal stage: row sums over the KS column taps, all LH rows.
        // Wave = one full row segment (64 consecutive entries) -> conflict-free.
        for (int e = tid; e < LH * 64; e += 1024) {
            const int r = e >> 6;
            const int c = e & 63;
            const float2* rp = &sv[r * LW + c];
            float hs = 0.0f, hs2 = 0.0f, hsl = 0.0f;
            #pragma unroll
            for (int mj = 0; mj < KS; ++mj) {
                const float2 p = rp[mj * D];
                hs  += p.x;
                hs2  = fmaf(p.x, p.x, hs2);
                hsl += p.y;
            }
            rs2[e] = make_float2(hs, hs2);
            rs1[e] = hsl;
        }
        __syncthreads();

        // Vertical stage: KS taps over row sums.
        #pragma unroll
        for (int mi = 0; mi < KS; ++mi) {
            const int rr = (ty + mi * D) * 64 + tx;
            const float2 q = rs2[rr];
            s  += q.x;
            s2 += q.y;
            sl += rs1[rr];
        }
        const float mu = s * INVK;

        // SAD pass: K taps (not separable; mu per-pixel). b32 reads, stride-1
        // across lanes -> 2-way bank alias (free); constant offset pairs are
        // ds_read2-mergeable by the compiler.
        const float2* base = &sv[ty * LW + tx];
        sad = 0.0f;
        #pragma unroll
        for (int mi = 0; mi < KS; ++mi)
            #pragma unroll
            for (int mj = 0; mj < KS; ++mj)
                sad += fabsf(base[(mi * D) * LW + mj * D].x - mu);
    }

    const float mu       = s * INVK;
    const float energy   = s2 * INVK;
    const float var      = fmaxf(energy - mu * mu, 0.0f);
    const float sd       = sqrtf(var * UNB) + EPS;
    const float contrast = var / (sd * sd);
    const float entropy  = -sl * INVK;
    const float homog    = 1.0f / (1.0f + sad * INVK);

    const size_t fstride = (size_t)H * W;
    const size_t rowoff  = (size_t)(h0 + ty) * W;
    float* op = out + (size_t)bc * 4 * fstride + w0 + tx;
    __builtin_nontemporal_store((contrast + EPS) * INV_SQRT_E, &op[0 * fstride + rowoff]);
    __builtin_nontemporal_store((energy   + EPS) * INV_SQRT_E, &op[1 * fstride + rowoff]);
    __builtin_nontemporal_store((entropy  + EPS) * INV_SQRT_E, &op[2 * fstride + rowoff]);
    __builtin_nontemporal_store((homog    + EPS) * INV_SQRT_E, &op[3 * fstride + rowoff]);
}

__global__ __launch_bounds__(1024, 4) void tex_fused(
    const float* __restrict__ x, float* __restrict__ out, int H, int W)
{
    extern __shared__ char smem[];
    const int dz = blockIdx.z & 3;       // dilation index 0..3 (fast bits)
    const int bc = blockIdx.z >> 2;      // b*C + c
    const size_t per = (size_t)8 * 4 * H * W;
    switch (dz) {
        case 0: body<1>(x, out + 0 * per, smem, bc, H, W); break;
        case 1: body<2>(x, out + 1 * per, smem, bc, H, W); break;
        case 2: body<3>(x, out + 2 * per, smem, bc, H, W); break;
        default: body<4>(x, out + 3 * per, smem, bc, H, W); break;
    }
}

extern "C" void kernel_launch(void* const* d_in, const int* in_sizes, int n_in,
                              void* d_out, int out_size, void* d_ws, size_t ws_size,
                              hipStream_t stream) {
    const float* x = (const float*)d_in[0];
    float* out = (float*)d_out;

    const int H = 256, W = 256;
    // D=4: sv 48*96*8 = 36864; rs2 48*64*8 = 24576; rs1 48*64*4 = 12288
    const size_t smem_bytes = 36864 + 24576 + 12288;   // 73728 B

    dim3 blk(64, 16, 1);
    dim3 grd(W / 64, H / 16, 8 * 4);     // (B*C=8) x 4 dilations
    tex_fused<<<grd, blk, smem_bytes, stream>>>(x, out, H, W);
}

// Round 7
// 79.668 us; speedup vs baseline: 2.1755x; 1.0753x over previous
//
#include <hip/hip_runtime.h>
#include <cstddef>

#define EPS 1e-6f
constexpr float INV_SQRT_E = 0.6065306597126334f;  // exp(-0.5*THETA^2), THETA=1

// Fused, all 4 dilations in one launch; tile 64x8, block (64,8)=8 waves ->
// 4096 blocks (16/CU queue) for load balance; heavy dilations (D=4) first.
// Pass-1 (s, s^2, sum p*log p) separable VERTICAL-FIRST: column sums cs[r][c]
// (r in [0,TH) only -> small plane, 3x less stage-1 traffic than row-first),
// then KS horizontal taps. SAD stays K-tap (mu is per-pixel).
// R6 bug fixed: D=4 needs LH = 8 + 2*16 = 40 rows; LDS now sized for it.
//   D=4: sv 40*96*8=30720 + cs 8*96*12=9216 -> 39936 B (max)
//   -> 4 blocks/CU x 8 waves = 32 waves/CU.
template <int D>
__device__ __forceinline__ void body(const float* __restrict__ x,
                                     float* __restrict__ out,
                                     char* smem, int bc, int H, int W)
{
    constexpr int PAD = D * D;          // halo per side
    constexpr int KS  = 2 * D + 1;      // taps per axis
    constexpr int K   = KS * KS;        // patch size
    constexpr int TW  = 64, TH = 8;
    constexpr int LW  = TW + 2 * PAD;
    constexpr int LH  = TH + 2 * PAD;
    constexpr float INVK = 1.0f / (float)K;
    constexpr float UNB  = (float)K / (float)(K - 1);

    float2* sv  = (float2*)smem;                          // {v, v*log(v+eps)}
    float2* cs2 = (float2*)(smem + LH * LW * 8);          // {col_s, col_s2}
    float*  cs1 = (float*) (smem + LH * LW * 8 + TH * LW * 8);  // col_sl

    const int w0 = blockIdx.x * TW;
    const int h0 = blockIdx.y * TH;
    const float* xp = x + (size_t)bc * H * W;

    const int tid = threadIdx.y * 64 + threadIdx.x;
    for (int idx = tid; idx < LH * LW; idx += 512) {
        const int r  = idx / LW;
        const int cc = idx - r * LW;
        const int gh = h0 - PAD + r;
        const int gw = w0 - PAD + cc;
        float v = 0.0f;
        if (gh >= 0 && gh < H && gw >= 0 && gw < W) v = xp[gh * W + gw];
        sv[idx] = make_float2(v, v * __logf(v + EPS));  // v=0 -> exactly 0
    }
    __syncthreads();

    const int tx = threadIdx.x;
    const int ty = threadIdx.y;

    float s = 0.0f, s2 = 0.0f, sl = 0.0f;
    float sad;

    if constexpr (K <= 9) {
        // D=1: single pass, taps cached in registers.
        const float2* base = &sv[ty * LW + tx];
        float ta[K];
        #pragma unroll
        for (int mi = 0; mi < KS; ++mi)
            #pragma unroll
            for (int mj = 0; mj < KS; ++mj) {
                const float2 p = base[(mi * D) * LW + mj * D];
                ta[mi * KS + mj] = p.x;
                s  += p.x;
                s2  = fmaf(p.x, p.x, s2);
                sl += p.y;
            }
        const float mu = s * INVK;
        sad = 0.0f;
        #pragma unroll
        for (int i = 0; i < K; ++i) sad += fabsf(ta[i] - mu);
    } else {
        // Vertical stage: column sums over KS row taps, TH x LW plane.
        // Consecutive lanes -> consecutive columns -> conflict-free.
        for (int e = tid; e < TH * LW; e += 512) {
            const int r = e / LW;                // output row
            const int c = e - r * LW;            // column in padded tile
            const float2* cp = &sv[r * LW + c];
            float vs = 0.0f, vs2 = 0.0f, vsl = 0.0f;
            #pragma unroll
            for (int mi = 0; mi < KS; ++mi) {
                const float2 p = cp[(mi * D) * LW];
                vs  += p.x;
                vs2  = fmaf(p.x, p.x, vs2);
                vsl += p.y;
            }
            cs2[e] = make_float2(vs, vs2);
            cs1[e] = vsl;
        }
        __syncthreads();

        // Horizontal stage: KS taps over column sums.
        const float2* q2 = &cs2[ty * LW + tx];
        const float*  q1 = &cs1[ty * LW + tx];
        #pragma unroll
        for (int mj = 0; mj < KS; ++mj) {
            const float2 q = q2[mj * D];
            s  += q.x;
            s2 += q.y;
            sl += q1[mj * D];
        }
        const float mu = s * INVK;

        // SAD pass: K taps (mu per-pixel; not separable).
        const float2* base = &sv[ty * LW + tx];
        sad = 0.0f;
        #pragma unroll
        for (int mi = 0; mi < KS; ++mi)
            #pragma unroll
            for (int mj = 0; mj < KS; ++mj)
                sad += fabsf(base[(mi * D) * LW + mj * D].x - mu);
    }

    const float mu       = s * INVK;
    const float energy   = s2 * INVK;
    const float var      = fmaxf(energy - mu * mu, 0.0f);
    const float sd       = sqrtf(var * UNB) + EPS;
    const float contrast = var / (sd * sd);
    const float entropy  = -sl * INVK;
    const float homog    = 1.0f / (1.0f + sad * INVK);

    const size_t fstride = (size_t)H * W;
    const size_t rowoff  = (size_t)(h0 + ty) * W;
    float* op = out + (size_t)bc * 4 * fstride + w0 + tx;
    __builtin_nontemporal_store((contrast + EPS) * INV_SQRT_E, &op[0 * fstride + rowoff]);
    __builtin_nontemporal_store((energy   + EPS) * INV_SQRT_E, &op[1 * fstride + rowoff]);
    __builtin_nontemporal_store((entropy  + EPS) * INV_SQRT_E, &op[2 * fstride + rowoff]);
    __builtin_nontemporal_store((homog    + EPS) * INV_SQRT_E, &op[3 * fstride + rowoff]);
}

__global__ __launch_bounds__(512, 8) void tex_fused(
    const float* __restrict__ x, float* __restrict__ out, int H, int W)
{
    extern __shared__ char smem[];
    const int dz = blockIdx.z >> 3;      // 0..3, heavy-first: 0->D4 ... 3->D1
    const int bc = blockIdx.z & 7;       // b*C + c
    const size_t per = (size_t)8 * 4 * H * W;
    switch (dz) {
        case 0: body<4>(x, out + 3 * per, smem, bc, H, W); break;
        case 1: body<3>(x, out + 2 * per, smem, bc, H, W); break;
        case 2: body<2>(x, out + 1 * per, smem, bc, H, W); break;
        default: body<1>(x, out + 0 * per, smem, bc, H, W); break;
    }
}

extern "C" void kernel_launch(void* const* d_in, const int* in_sizes, int n_in,
                              void* d_out, int out_size, void* d_ws, size_t ws_size,
                              hipStream_t stream) {
    const float* x = (const float*)d_in[0];
    float* out = (float*)d_out;

    const int H = 256, W = 256;
    // Per-D LDS (TH=8, PAD=D*D): sv LH*LW*8 + cs TH*LW*12
    //   D=4: LH=40, LW=96: 30720 + 9216 = 39936  (max)
    //   D=3: LH=26, LW=82: 17056 + 7872 = 24928
    //   D=2: LH=16, LW=72:  9216 + 6912 = 16128
    //   D=1: LH=10, LW=66:  5280 (register path)
    const size_t smem_bytes = 39936;

    dim3 blk(64, 8, 1);
    dim3 grd(W / 64, H / 8, 8 * 4);      // 4 x-tiles, 32 y-tiles, (bc x dz)
    tex_fused<<<grd, blk, smem_bytes, stream>>>(x, out, H, W);
}